// Round 11
// baseline (574.830 us; speedup 1.0000x reference)
//
#include <hip/hip_runtime.h>
#include <math.h>

typedef __attribute__((ext_vector_type(8)))  short s16x8;   // 8 bf16 (4 VGPRs)
typedef __attribute__((ext_vector_type(16))) float f32x16;  // MFMA 32x32 acc
typedef __attribute__((ext_vector_type(4)))  int   v4i;     // nt-loadable int4

__device__ inline float bf_lo(unsigned u) { return __uint_as_float(u << 16); }
__device__ inline float bf_hi(unsigned u) { return __uint_as_float(u & 0xffff0000u); }
__device__ inline unsigned short f2bf(float f) {           // RNE f32 -> bf16
    unsigned u = __float_as_uint(f);
    u += 0x7fffu + ((u >> 16) & 1u);
    return (unsigned short)(u >> 16);
}

// ===========================================================================
// Fused prep: x f32->bf16, 6 weight transposes, deg zeroing. One dispatch.
// ===========================================================================
__global__ __launch_bounds__(256)
void prep_fused(const float* __restrict__ x,   unsigned short* __restrict__ xbf,
                const float* __restrict__ W1a, unsigned short* __restrict__ W1aT,
                const float* __restrict__ W1b, unsigned short* __restrict__ W1bT,
                const float* __restrict__ W2a, unsigned short* __restrict__ W2aT,
                const float* __restrict__ W2b, unsigned short* __restrict__ W2bT,
                const float* __restrict__ W3a, unsigned short* __restrict__ W3aT,
                const float* __restrict__ W3b, unsigned short* __restrict__ W3bT,
                int* __restrict__ deg, int N) {
    int i = blockIdx.x * 256 + threadIdx.x;
    int nx = N * 48;
    if (i < nx) { xbf[i] = f2bf(x[i]); return; }
    i -= nx;
    if (i < N) { deg[i] = 0; return; }
    i -= N;
    if (i < 256 * 96)  { int n = i / 96,  k = i - n * 96;  W1aT[i] = f2bf(W1a[(size_t)k * 256 + n]); return; }
    i -= 256 * 96;
    if (i < 128 * 256) { int n = i / 256, k = i - n * 256; W1bT[i] = f2bf(W1b[(size_t)k * 128 + n]); return; }
    i -= 128 * 256;
    if (i < 256 * 304) { int n = i / 304, k = i - n * 304; W2aT[i] = f2bf(W2a[(size_t)k * 256 + n]); return; }
    i -= 256 * 304;
    if (i < 128 * 256) { int n = i / 256, k = i - n * 256; W2bT[i] = f2bf(W2b[(size_t)k * 128 + n]); return; }
    i -= 128 * 256;
    if (i < 256 * 304) { int n = i / 304, k = i - n * 304; W3aT[i] = f2bf(W3a[(size_t)k * 256 + n]); return; }
    i -= 256 * 304;
    if (i < 64 * 256)  { int n = i / 256, k = i - n * 256;
                         float v = (n < 40) ? W3b[(size_t)k * 40 + n] : 0.f;
                         W3bT[i] = f2bf(v); return; }
}

// ===========================================================================
// CSR build (by dst), XCD-matched range ownership + NON-TEMPORAL streams.
// Round-10 counters: FETCH 50MB = 8 XCDs x full dst stream through L2;
// that stream evicted dirty csr lines before their 16 writes merged
// (WRITE 80MB for 6.4MB payload). nt loads keep the stream from displacing
// the L2-resident cursor/csr write window.
// ===========================================================================
__global__ __launch_bounds__(256)
void deg_hist_xcd(const int* __restrict__ dst, int* __restrict__ deg,
                  int E, int N) {
    const int r     = blockIdx.x & 7;
    const int sb    = blockIdx.x >> 3;
    const int nsl   = gridDim.x >> 3;
    const int chunk = (N + 7) / 8;
    const int lo = r * chunk;
    const int hi = min(lo + chunk, N);
    const int nq = E >> 2;
    const v4i* dst4 = (const v4i*)dst;
    for (int q = sb * 256 + threadIdx.x; q < nq; q += nsl * 256) {
        const v4i d4 = __builtin_nontemporal_load(dst4 + q);
        if (d4.x >= lo && d4.x < hi) atomicAdd(&deg[d4.x], 1);
        if (d4.y >= lo && d4.y < hi) atomicAdd(&deg[d4.y], 1);
        if (d4.z >= lo && d4.z < hi) atomicAdd(&deg[d4.z], 1);
        if (d4.w >= lo && d4.w < hi) atomicAdd(&deg[d4.w], 1);
    }
    if (sb == 0) {
        for (int e = nq * 4 + threadIdx.x; e < E; e += 256) {
            int d = dst[e];
            if (d >= lo && d < hi) atomicAdd(&deg[d], 1);
        }
    }
}

__global__ __launch_bounds__(256)
void scan_block_sums(const int* __restrict__ deg, int* __restrict__ bsum, int N) {
    __shared__ int sh[256];
    int base = blockIdx.x * 1024 + threadIdx.x * 4;
    int s = 0;
    #pragma unroll
    for (int k = 0; k < 4; ++k) { int i = base + k; if (i < N) s += deg[i]; }
    sh[threadIdx.x] = s;
    __syncthreads();
    for (int off = 128; off >= 1; off >>= 1) {
        if (threadIdx.x < off) sh[threadIdx.x] += sh[threadIdx.x + off];
        __syncthreads();
    }
    if (threadIdx.x == 0) bsum[blockIdx.x] = sh[0];
}

__global__ __launch_bounds__(256)
void scan_bsums(int* __restrict__ bsum, int nb) {
    __shared__ int sh[256];
    int t = threadIdx.x;
    int v = (t < nb) ? bsum[t] : 0;
    sh[t] = v;
    __syncthreads();
    for (int off = 1; off < 256; off <<= 1) {
        int add = (t >= off) ? sh[t - off] : 0;
        __syncthreads();
        sh[t] += add;
        __syncthreads();
    }
    if (t < nb) bsum[t] = sh[t] - v;
}

__global__ __launch_bounds__(256)
void scan_finalize(const int* __restrict__ deg, const int* __restrict__ bsum,
                   int* __restrict__ rowptr, int* __restrict__ cursor, int N) {
    __shared__ int sh[256];
    int t = threadIdx.x;
    int base = blockIdx.x * 1024 + t * 4;
    int loc[4];
    int s = 0;
    #pragma unroll
    for (int k = 0; k < 4; ++k) {
        int i = base + k;
        loc[k] = (i < N) ? deg[i] : 0;
        s += loc[k];
    }
    sh[t] = s;
    __syncthreads();
    for (int off = 1; off < 256; off <<= 1) {
        int add = (t >= off) ? sh[t - off] : 0;
        __syncthreads();
        sh[t] += add;
        __syncthreads();
    }
    int run = bsum[blockIdx.x] + sh[t] - s;
    #pragma unroll
    for (int k = 0; k < 4; ++k) {
        int i = base + k;
        if (i < N) { rowptr[i] = run; cursor[i] = run; }
        run += loc[k];
    }
}

__global__ __launch_bounds__(256)
void csr_scatter_xcd(const int* __restrict__ src, const int* __restrict__ dst,
                     int* __restrict__ cursor, int* __restrict__ csr_src,
                     int E, int N) {
    const int r     = blockIdx.x & 7;
    const int sb    = blockIdx.x >> 3;
    const int nsl   = gridDim.x >> 3;
    const int chunk = (N + 7) / 8;
    const int lo = r * chunk;
    const int hi = min(lo + chunk, N);
    const int nq = E >> 2;
    const v4i* dst4 = (const v4i*)dst;
    for (int q = sb * 256 + threadIdx.x; q < nq; q += nsl * 256) {
        const v4i d4 = __builtin_nontemporal_load(dst4 + q);
        const int e = q * 4;
        if (d4.x >= lo && d4.x < hi) { int p = atomicAdd(&cursor[d4.x], 1); if (p < E) csr_src[p] = __builtin_nontemporal_load(src + e + 0); }
        if (d4.y >= lo && d4.y < hi) { int p = atomicAdd(&cursor[d4.y], 1); if (p < E) csr_src[p] = __builtin_nontemporal_load(src + e + 1); }
        if (d4.z >= lo && d4.z < hi) { int p = atomicAdd(&cursor[d4.z], 1); if (p < E) csr_src[p] = __builtin_nontemporal_load(src + e + 2); }
        if (d4.w >= lo && d4.w < hi) { int p = atomicAdd(&cursor[d4.w], 1); if (p < E) csr_src[p] = __builtin_nontemporal_load(src + e + 3); }
    }
    if (sb == 0) {
        for (int e = nq * 4 + threadIdx.x; e < E; e += 256) {
            int d = dst[e];
            if (d >= lo && d < hi) { int p = atomicAdd(&cursor[d], 1); if (p < E) csr_src[p] = src[e]; }
        }
    }
}

// ===========================================================================
// LGConv gather, bf16 in/out, f32 accumulate. 8 channels (16B) per lane.
// csr_src stream is nt so it doesn't displace the x-row working set in L2.
// ===========================================================================
template<int D, int LPN>
__global__ __launch_bounds__(256)
void lgconv_gather_bf16(const unsigned short* __restrict__ x,
                        const int* __restrict__ rowptr,
                        const int* __restrict__ deg,
                        const int* __restrict__ csr_src,
                        unsigned short* __restrict__ out, int N) {
    const int g    = (blockIdx.x * 256 + threadIdx.x) / LPN;
    const int lane = threadIdx.x & (LPN - 1);
    if (g >= N) return;
    if (lane * 8 >= D) return;
    const int start = rowptr[g];
    const int dg    = deg[g];
    float acc[8] = {0.f,0.f,0.f,0.f,0.f,0.f,0.f,0.f};
    int j = 0;
    for (; j + 1 < dg; j += 2) {
        int s0 = __builtin_nontemporal_load(csr_src + start + j);
        int s1 = __builtin_nontemporal_load(csr_src + start + j + 1);
        uint4 v0 = *(const uint4*)(x + (size_t)s0 * D + lane * 8);
        uint4 v1 = *(const uint4*)(x + (size_t)s1 * D + lane * 8);
        acc[0] += bf_lo(v0.x); acc[1] += bf_hi(v0.x);
        acc[2] += bf_lo(v0.y); acc[3] += bf_hi(v0.y);
        acc[4] += bf_lo(v0.z); acc[5] += bf_hi(v0.z);
        acc[6] += bf_lo(v0.w); acc[7] += bf_hi(v0.w);
        acc[0] += bf_lo(v1.x); acc[1] += bf_hi(v1.x);
        acc[2] += bf_lo(v1.y); acc[3] += bf_hi(v1.y);
        acc[4] += bf_lo(v1.z); acc[5] += bf_hi(v1.z);
        acc[6] += bf_lo(v1.w); acc[7] += bf_hi(v1.w);
    }
    if (j < dg) {
        int s0 = __builtin_nontemporal_load(csr_src + start + j);
        uint4 v0 = *(const uint4*)(x + (size_t)s0 * D + lane * 8);
        acc[0] += bf_lo(v0.x); acc[1] += bf_hi(v0.x);
        acc[2] += bf_lo(v0.y); acc[3] += bf_hi(v0.y);
        acc[4] += bf_lo(v0.z); acc[5] += bf_hi(v0.z);
        acc[6] += bf_lo(v0.w); acc[7] += bf_hi(v0.w);
    }
    uint4 o;
    o.x = ((unsigned)f2bf(acc[1]) << 16) | f2bf(acc[0]);
    o.y = ((unsigned)f2bf(acc[3]) << 16) | f2bf(acc[2]);
    o.z = ((unsigned)f2bf(acc[5]) << 16) | f2bf(acc[4]);
    o.w = ((unsigned)f2bf(acc[7]) << 16) | f2bf(acc[6]);
    *(uint4*)(out + (size_t)g * D + lane * 8) = o;
}

// ===========================================================================
// Fused 2-layer MLP, bf16 MFMA (32x32x16), 64 rows/block, 4 waves.
// A-tile staged in LDS (round-10 win); A unions with hid; LDS <=40KB.
// ===========================================================================
template<int LA, int LB, int LC, bool LSM>
__global__ __launch_bounds__(256)
void fused_mlp_mfma(const unsigned short* __restrict__ segA,
                    const unsigned short* __restrict__ segB,
                    const unsigned short* __restrict__ segC,
                    const unsigned short* __restrict__ WaT, const float* __restrict__ ba,
                    const unsigned short* __restrict__ WbT, const float* __restrict__ bb,
                    void* __restrict__ outv, int n) {
    constexpr int K1   = LA + LB + LC;      // 96 or 304
    constexpr int NS1  = K1 / 16;
    constexpr int NCH  = K1 / 8;            // 16B chunks per row
    constexpr int KPAD = K1 + 8;            // 104 or 312 (16B-aligned rows)
    constexpr int K2P  = 264;               // hid row stride (bf16)
    constexpr int SW   = (64 * KPAD > 64 * K2P) ? 64 * KPAD : 64 * K2P;
    __shared__ __attribute__((aligned(16))) unsigned short smem[SW];
    unsigned short* Ab  = smem;             // stage-1 A tile   [64][KPAD]
    unsigned short* hid = smem;             // stage-1 out      [64][K2P] (union)

    const int tid  = threadIdx.x;
    const int wave = tid >> 6;
    const int lane = tid & 63;
    const int l31  = lane & 31;
    const int lh   = lane >> 5;
    const int row0 = blockIdx.x * 64;

    // ---- stage A tile: coalesced uint4, ~10 independent loads/thread ----
    for (int c = tid; c < 64 * NCH; c += 256) {
        const int m  = c / NCH;
        const int kc = c - m * NCH;
        const int row = row0 + m;
        const int ra  = (row < n) ? row : (n - 1);
        const unsigned short* sp;
        int koff;
        if (kc * 8 < LA)           { sp = segA + (size_t)ra * LA; koff = kc * 8; }
        else if (kc * 8 < LA + LB) { sp = segB + (size_t)ra * LB; koff = kc * 8 - LA; }
        else                       { sp = segC + (size_t)ra * LC; koff = kc * 8 - LA - LB; }
        *(uint4*)(Ab + m * KPAD + kc * 8) = *(const uint4*)(sp + koff);
    }
    __syncthreads();

    // ---------------- stage 1 ----------------
    f32x16 acc00 = {}, acc01 = {}, acc10 = {}, acc11 = {};
    const unsigned short* wa0 = WaT + (size_t)(wave * 64 + l31) * K1 + lh * 8;
    const unsigned short* wa1 = wa0 + (size_t)32 * K1;
    const int a0off = l31 * KPAD + lh * 8;
    const int a1off = (l31 + 32) * KPAD + lh * 8;

    #pragma unroll
    for (int s = 0; s < NS1; ++s) {
        const int k0 = s * 16;
        s16x8 a0 = *(const s16x8*)(Ab + a0off + k0);
        s16x8 a1 = *(const s16x8*)(Ab + a1off + k0);
        s16x8 b0 = *(const s16x8*)(wa0 + k0);
        s16x8 b1 = *(const s16x8*)(wa1 + k0);
        acc00 = __builtin_amdgcn_mfma_f32_32x32x16_bf16(a0, b0, acc00, 0, 0, 0);
        acc01 = __builtin_amdgcn_mfma_f32_32x32x16_bf16(a0, b1, acc01, 0, 0, 0);
        acc10 = __builtin_amdgcn_mfma_f32_32x32x16_bf16(a1, b0, acc10, 0, 0, 0);
        acc11 = __builtin_amdgcn_mfma_f32_32x32x16_bf16(a1, b1, acc11, 0, 0, 0);
    }
    __syncthreads();                        // all A reads done before hid overwrites

    // epilogue: + bias, relu -> hid[m][k] bf16 (C/D layout, m74/m101)
    {
        const int c0 = wave * 64 + l31;
        const int c1 = c0 + 32;
        const float bias0 = ba[c0];
        const float bias1 = ba[c1];
        #pragma unroll
        for (int t = 0; t < 16; ++t) {
            int rloc = (t & 3) + 8 * (t >> 2) + 4 * lh;
            hid[rloc * K2P + c0]        = f2bf(fmaxf(acc00[t] + bias0, 0.f));
            hid[rloc * K2P + c1]        = f2bf(fmaxf(acc01[t] + bias1, 0.f));
            hid[(rloc + 32) * K2P + c0] = f2bf(fmaxf(acc10[t] + bias0, 0.f));
            hid[(rloc + 32) * K2P + c1] = f2bf(fmaxf(acc11[t] + bias1, 0.f));
        }
    }
    __syncthreads();

    // ---------------- stage 2 ----------------
    if (!LSM) {
        f32x16 d0 = {}, d1 = {};
        const unsigned short* wb = WbT + (size_t)(wave * 32 + l31) * 256 + lh * 8;
        const int h0 = l31 * K2P + lh * 8;
        #pragma unroll
        for (int s = 0; s < 16; ++s) {
            s16x8 a0 = *(const s16x8*)&hid[h0 + s * 16];
            s16x8 a1 = *(const s16x8*)&hid[h0 + 32 * K2P + s * 16];
            s16x8 b  = *(const s16x8*)(wb + s * 16);
            d0 = __builtin_amdgcn_mfma_f32_32x32x16_bf16(a0, b, d0, 0, 0, 0);
            d1 = __builtin_amdgcn_mfma_f32_32x32x16_bf16(a1, b, d1, 0, 0, 0);
        }
        const int col = wave * 32 + l31;
        const float bias = bb[col];
        unsigned short* out = (unsigned short*)outv;
        #pragma unroll
        for (int t = 0; t < 16; ++t) {
            int rloc = (t & 3) + 8 * (t >> 2) + 4 * lh;
            int rr0 = row0 + rloc, rr1 = rr0 + 32;
            if (rr0 < n) out[(size_t)rr0 * 128 + col] = f2bf(fmaxf(d0[t] + bias, 0.f));
            if (rr1 < n) out[(size_t)rr1 * 128 + col] = f2bf(fmaxf(d1[t] + bias, 0.f));
        }
    } else {
        const int rt = wave & 1, ct = wave >> 1;
        f32x16 d = {};
        const unsigned short* wb = WbT + (size_t)(ct * 32 + l31) * 256 + lh * 8;
        const int h0 = (rt * 32 + l31) * K2P + lh * 8;
        #pragma unroll
        for (int s = 0; s < 16; ++s) {
            s16x8 a = *(const s16x8*)&hid[h0 + s * 16];
            s16x8 b = *(const s16x8*)(wb + s * 16);
            d = __builtin_amdgcn_mfma_f32_32x32x16_bf16(a, b, d, 0, 0, 0);
        }
        __syncthreads();                    // done reading hid; reuse as logits
        float* lg = (float*)smem;           // [64][68] f32 = 17.4KB
        const int col = ct * 32 + l31;
        const float bias = (col < 40) ? bb[col] : 0.f;
        #pragma unroll
        for (int t = 0; t < 16; ++t) {
            int rloc = rt * 32 + (t & 3) + 8 * (t >> 2) + 4 * lh;
            lg[rloc * 68 + col] = d[t] + bias;
        }
        __syncthreads();
        const int r = tid >> 2, j = tid & 3;
        float mx = -1e30f;
        #pragma unroll
        for (int c = 0; c < 10; ++c) mx = fmaxf(mx, lg[r * 68 + j * 10 + c]);
        mx = fmaxf(mx, __shfl_xor(mx, 1));
        mx = fmaxf(mx, __shfl_xor(mx, 2));
        float sm = 0.f;
        #pragma unroll
        for (int c = 0; c < 10; ++c) sm += __expf(lg[r * 68 + j * 10 + c] - mx);
        sm += __shfl_xor(sm, 1);
        sm += __shfl_xor(sm, 2);
        const float lse = mx + __logf(sm);
        const int row = row0 + r;
        float* out = (float*)outv;
        if (row < n) {
            #pragma unroll
            for (int c = 0; c < 10; ++c)
                out[(size_t)row * 40 + j * 10 + c] = lg[r * 68 + j * 10 + c] - lse;
        }
    }
}

// ===========================================================================
extern "C" void kernel_launch(void* const* d_in, const int* in_sizes, int n_in,
                              void* d_out, int out_size, void* d_ws, size_t ws_size,
                              hipStream_t stream) {
    const float* x   = (const float*)d_in[0];
    const int*   ei  = (const int*)d_in[1];
    const float* W1a = (const float*)d_in[2];
    const float* b1a = (const float*)d_in[3];
    const float* W1b = (const float*)d_in[4];
    const float* b1b = (const float*)d_in[5];
    const float* W2a = (const float*)d_in[6];
    const float* b2a = (const float*)d_in[7];
    const float* W2b = (const float*)d_in[8];
    const float* b2b = (const float*)d_in[9];
    const float* W3a = (const float*)d_in[10];
    const float* b3a = (const float*)d_in[11];
    const float* W3b = (const float*)d_in[12];
    const float* b3b = (const float*)d_in[13];
    float* out = (float*)d_out;

    const int E = in_sizes[1] / 2;
    const int N = in_sizes[0] / 48;
    const int* src = ei;
    const int* dst = ei + E;

    // ---- workspace carve-up (256B aligned) ----
    char* p = (char*)d_ws;
    auto alloc = [&](size_t bytes) { void* q = p; p += (bytes + 255) & ~(size_t)255; return q; };
    unsigned short* xbf  = (unsigned short*)alloc((size_t)N * 48  * 2);
    unsigned short* c1   = (unsigned short*)alloc((size_t)N * 48  * 2);
    unsigned short* h1   = (unsigned short*)alloc((size_t)N * 128 * 2);
    unsigned short* c2   = (unsigned short*)alloc((size_t)N * 128 * 2);  // also c3
    unsigned short* h2   = (unsigned short*)alloc((size_t)N * 128 * 2);
    unsigned short* W1aT = (unsigned short*)alloc((size_t)256 * 96  * 2);
    unsigned short* W1bT = (unsigned short*)alloc((size_t)128 * 256 * 2);
    unsigned short* W2aT = (unsigned short*)alloc((size_t)256 * 304 * 2);
    unsigned short* W2bT = (unsigned short*)alloc((size_t)128 * 256 * 2);
    unsigned short* W3aT = (unsigned short*)alloc((size_t)256 * 304 * 2);
    unsigned short* W3bT = (unsigned short*)alloc((size_t)64  * 256 * 2);
    int* deg     = (int*)alloc((size_t)N * 4);
    int* rowptr  = (int*)alloc((size_t)N * 4);
    int* cursor  = (int*)alloc((size_t)N * 4);
    int* bsum    = (int*)alloc(1024);
    int* csr_src = (int*)alloc((size_t)E * 4);

    const int nb_scan = (N + 1023) / 1024;
    const int nblk    = (N + 63) / 64;

    // ---- fused prep (x->bf16, 6 transposes, deg=0) ----
    {
        int total = N * 48 + N + 256*96 + 128*256 + 256*304 + 128*256 + 256*304 + 64*256;
        prep_fused<<<(total + 255) / 256, 256, 0, stream>>>(
            x, xbf, W1a, W1aT, W1b, W1bT, W2a, W2aT, W2b, W2bT,
            W3a, W3aT, W3b, W3bT, deg, N);
    }

    // ---- CSR build ----
    deg_hist_xcd<<<2048, 256, 0, stream>>>(dst, deg, E, N);
    scan_block_sums<<<nb_scan, 256, 0, stream>>>(deg, bsum, N);
    scan_bsums<<<1, 256, 0, stream>>>(bsum, nb_scan);
    scan_finalize<<<nb_scan, 256, 0, stream>>>(deg, bsum, rowptr, cursor, N);
    csr_scatter_xcd<<<2048, 256, 0, stream>>>(src, dst, cursor, csr_src, E, N);

    // ---- layer 1 ----
    lgconv_gather_bf16<48, 8><<<((size_t)N * 8 + 255) / 256, 256, 0, stream>>>(
        xbf, rowptr, deg, csr_src, c1, N);
    fused_mlp_mfma<48, 48, 0, false><<<nblk, 256, 0, stream>>>(
        c1, xbf, (const unsigned short*)nullptr, W1aT, b1a, W1bT, b1b, h1, N);

    // ---- layer 2 ----
    lgconv_gather_bf16<128, 16><<<((size_t)N * 16 + 255) / 256, 256, 0, stream>>>(
        h1, rowptr, deg, csr_src, c2, N);
    fused_mlp_mfma<128, 128, 48, false><<<nblk, 256, 0, stream>>>(
        c2, h1, xbf, W2aT, b2a, W2bT, b2b, h2, N);

    // ---- layer 3 ----
    lgconv_gather_bf16<128, 16><<<((size_t)N * 16 + 255) / 256, 256, 0, stream>>>(
        h2, rowptr, deg, csr_src, c2, N);   // c3 reuses c2 slot
    fused_mlp_mfma<128, 128, 48, true><<<nblk, 256, 0, stream>>>(
        c2, h2, xbf, W3aT, b3a, W3bT, b3b, out, N);
}

// Round 12
// 560.738 us; speedup vs baseline: 1.0251x; 1.0251x over previous
//
#include <hip/hip_runtime.h>
#include <math.h>

typedef __attribute__((ext_vector_type(8)))  short s16x8;   // 8 bf16 (4 VGPRs)
typedef __attribute__((ext_vector_type(16))) float f32x16;  // MFMA 32x32 acc

__device__ inline float bf_lo(unsigned u) { return __uint_as_float(u << 16); }
__device__ inline float bf_hi(unsigned u) { return __uint_as_float(u & 0xffff0000u); }
__device__ inline unsigned short f2bf(float f) {           // RNE f32 -> bf16
    unsigned u = __float_as_uint(f);
    u += 0x7fffu + ((u >> 16) & 1u);
    return (unsigned short)(u >> 16);
}

#define BMAX 3200   // max edges per producer chunk (LDS-resident)

// ===========================================================================
// Fused prep: x f32->bf16, 6 weight transposes, deg zeroing. One dispatch.
// ===========================================================================
__global__ __launch_bounds__(256)
void prep_fused(const float* __restrict__ x,   unsigned short* __restrict__ xbf,
                const float* __restrict__ W1a, unsigned short* __restrict__ W1aT,
                const float* __restrict__ W1b, unsigned short* __restrict__ W1bT,
                const float* __restrict__ W2a, unsigned short* __restrict__ W2aT,
                const float* __restrict__ W2b, unsigned short* __restrict__ W2bT,
                const float* __restrict__ W3a, unsigned short* __restrict__ W3aT,
                const float* __restrict__ W3b, unsigned short* __restrict__ W3bT,
                int* __restrict__ deg, int N) {
    int i = blockIdx.x * 256 + threadIdx.x;
    int nx = N * 48;
    if (i < nx) { xbf[i] = f2bf(x[i]); return; }
    i -= nx;
    if (i < N) { deg[i] = 0; return; }
    i -= N;
    if (i < 256 * 96)  { int n = i / 96,  k = i - n * 96;  W1aT[i] = f2bf(W1a[(size_t)k * 256 + n]); return; }
    i -= 256 * 96;
    if (i < 128 * 256) { int n = i / 256, k = i - n * 256; W1bT[i] = f2bf(W1b[(size_t)k * 128 + n]); return; }
    i -= 128 * 256;
    if (i < 256 * 304) { int n = i / 304, k = i - n * 304; W2aT[i] = f2bf(W2a[(size_t)k * 256 + n]); return; }
    i -= 256 * 304;
    if (i < 128 * 256) { int n = i / 256, k = i - n * 256; W2bT[i] = f2bf(W2b[(size_t)k * 128 + n]); return; }
    i -= 128 * 256;
    if (i < 256 * 304) { int n = i / 304, k = i - n * 304; W3aT[i] = f2bf(W3a[(size_t)k * 256 + n]); return; }
    i -= 256 * 304;
    if (i < 64 * 256)  { int n = i / 256, k = i - n * 256;
                         float v = (n < 40) ? W3b[(size_t)k * 40 + n] : 0.f;
                         W3bT[i] = f2bf(v); return; }
}

// ===========================================================================
// Two-phase bucketed CSR build.
// Round-11 evidence: any scheme where range-owner blocks filter-scan the FULL
// dst array pays 8x stream reads per XCD (FETCH 50-68MB) and the stream
// evicts the dirty csr window (WRITE 68-80MB for 6.4MB payload). Fix the
// structure: producers compact edges by XCD range once (LDS-local, coalesced,
// block-private output windows), consumers then read only their range's
// 1.6MB of pairs -> write window stays L2-resident.
// ===========================================================================
__global__ __launch_bounds__(256)
void bucketize(const int* __restrict__ src, const int* __restrict__ dst,
               int2* __restrict__ pairs, int* __restrict__ offsg,
               int E, int N, int C) {
    __shared__ int sdst[BMAX];
    __shared__ int ssrc[BMAX];
    __shared__ int cnt[8], offs[9], cur[8];
    const int p    = blockIdx.x;
    const int base = p * C;
    const int len  = min(C, E - base);
    const int chunkN = (N + 7) / 8;
    if (threadIdx.x < 8) { cnt[threadIdx.x] = 0; cur[threadIdx.x] = 0; }
    for (int i = threadIdx.x; i < len; i += 256) {
        sdst[i] = dst[base + i];
        ssrc[i] = src[base + i];
    }
    __syncthreads();
    // count ranges (per-thread regs -> 8 LDS atomics/thread)
    int loc[8] = {0,0,0,0,0,0,0,0};
    for (int i = threadIdx.x; i < len; i += 256) {
        int r = sdst[i] / chunkN;
        loc[r < 7 ? r : 7]++;
    }
    #pragma unroll
    for (int r = 0; r < 8; ++r) if (loc[r]) atomicAdd(&cnt[r], loc[r]);
    __syncthreads();
    if (threadIdx.x == 0) {
        int s = 0;
        #pragma unroll
        for (int r = 0; r < 8; ++r) { offs[r] = s; s += cnt[r]; }
        offs[8] = s;
    }
    __syncthreads();
    // place compacted (order within range irrelevant: conv sums)
    for (int i = threadIdx.x; i < len; i += 256) {
        int d = sdst[i];
        int r = d / chunkN; r = r < 7 ? r : 7;
        int pos = offs[r] + atomicAdd(&cur[r], 1);
        pairs[base + pos] = make_int2(ssrc[i], d);
    }
    if (threadIdx.x < 9) offsg[p * 9 + threadIdx.x] = offs[threadIdx.x];
}

// consumers: grid 2048, range r = b&7 (XCD-matched), j = b>>3 walks producers
__global__ __launch_bounds__(256)
void deg_from_buckets(const int2* __restrict__ pairs, const int* __restrict__ offsg,
                      int* __restrict__ deg, int nprod, int C) {
    const int r = blockIdx.x & 7;
    const int j = blockIdx.x >> 3;
    for (int p = j; p < nprod; p += 256) {
        const int o0 = offsg[p * 9 + r];
        const int o1 = offsg[p * 9 + r + 1];
        const int base = p * C;
        for (int i = o0 + threadIdx.x; i < o1; i += 256)
            atomicAdd(&deg[pairs[base + i].y], 1);
    }
}

__global__ __launch_bounds__(256)
void place_from_buckets(const int2* __restrict__ pairs, const int* __restrict__ offsg,
                        int* __restrict__ cursor, int* __restrict__ csr_src,
                        int nprod, int C, int E) {
    const int r = blockIdx.x & 7;
    const int j = blockIdx.x >> 3;
    for (int p = j; p < nprod; p += 256) {
        const int o0 = offsg[p * 9 + r];
        const int o1 = offsg[p * 9 + r + 1];
        const int base = p * C;
        for (int i = o0 + threadIdx.x; i < o1; i += 256) {
            int2 pr = pairs[base + i];
            int pos = atomicAdd(&cursor[pr.y], 1);
            if (pos < E) csr_src[pos] = pr.x;
        }
    }
}

__global__ __launch_bounds__(256)
void scan_block_sums(const int* __restrict__ deg, int* __restrict__ bsum, int N) {
    __shared__ int sh[256];
    int base = blockIdx.x * 1024 + threadIdx.x * 4;
    int s = 0;
    #pragma unroll
    for (int k = 0; k < 4; ++k) { int i = base + k; if (i < N) s += deg[i]; }
    sh[threadIdx.x] = s;
    __syncthreads();
    for (int off = 128; off >= 1; off >>= 1) {
        if (threadIdx.x < off) sh[threadIdx.x] += sh[threadIdx.x + off];
        __syncthreads();
    }
    if (threadIdx.x == 0) bsum[blockIdx.x] = sh[0];
}

__global__ __launch_bounds__(256)
void scan_bsums(int* __restrict__ bsum, int nb) {
    __shared__ int sh[256];
    int t = threadIdx.x;
    int v = (t < nb) ? bsum[t] : 0;
    sh[t] = v;
    __syncthreads();
    for (int off = 1; off < 256; off <<= 1) {
        int add = (t >= off) ? sh[t - off] : 0;
        __syncthreads();
        sh[t] += add;
        __syncthreads();
    }
    if (t < nb) bsum[t] = sh[t] - v;
}

__global__ __launch_bounds__(256)
void scan_finalize(const int* __restrict__ deg, const int* __restrict__ bsum,
                   int* __restrict__ rowptr, int* __restrict__ cursor, int N) {
    __shared__ int sh[256];
    int t = threadIdx.x;
    int base = blockIdx.x * 1024 + t * 4;
    int loc[4];
    int s = 0;
    #pragma unroll
    for (int k = 0; k < 4; ++k) {
        int i = base + k;
        loc[k] = (i < N) ? deg[i] : 0;
        s += loc[k];
    }
    sh[t] = s;
    __syncthreads();
    for (int off = 1; off < 256; off <<= 1) {
        int add = (t >= off) ? sh[t - off] : 0;
        __syncthreads();
        sh[t] += add;
        __syncthreads();
    }
    int run = bsum[blockIdx.x] + sh[t] - s;
    #pragma unroll
    for (int k = 0; k < 4; ++k) {
        int i = base + k;
        if (i < N) { rowptr[i] = run; cursor[i] = run; }
        run += loc[k];
    }
}

// ===========================================================================
// LGConv gather, bf16 in/out, f32 accumulate. 8 channels (16B) per lane.
// (plain loads — round-11 nt experiment regressed, reverted)
// ===========================================================================
template<int D, int LPN>
__global__ __launch_bounds__(256)
void lgconv_gather_bf16(const unsigned short* __restrict__ x,
                        const int* __restrict__ rowptr,
                        const int* __restrict__ deg,
                        const int* __restrict__ csr_src,
                        unsigned short* __restrict__ out, int N) {
    const int g    = (blockIdx.x * 256 + threadIdx.x) / LPN;
    const int lane = threadIdx.x & (LPN - 1);
    if (g >= N) return;
    if (lane * 8 >= D) return;
    const int start = rowptr[g];
    const int dg    = deg[g];
    float acc[8] = {0.f,0.f,0.f,0.f,0.f,0.f,0.f,0.f};
    int j = 0;
    for (; j + 1 < dg; j += 2) {
        int s0 = csr_src[start + j];
        int s1 = csr_src[start + j + 1];
        uint4 v0 = *(const uint4*)(x + (size_t)s0 * D + lane * 8);
        uint4 v1 = *(const uint4*)(x + (size_t)s1 * D + lane * 8);
        acc[0] += bf_lo(v0.x); acc[1] += bf_hi(v0.x);
        acc[2] += bf_lo(v0.y); acc[3] += bf_hi(v0.y);
        acc[4] += bf_lo(v0.z); acc[5] += bf_hi(v0.z);
        acc[6] += bf_lo(v0.w); acc[7] += bf_hi(v0.w);
        acc[0] += bf_lo(v1.x); acc[1] += bf_hi(v1.x);
        acc[2] += bf_lo(v1.y); acc[3] += bf_hi(v1.y);
        acc[4] += bf_lo(v1.z); acc[5] += bf_hi(v1.z);
        acc[6] += bf_lo(v1.w); acc[7] += bf_hi(v1.w);
    }
    if (j < dg) {
        int s0 = csr_src[start + j];
        uint4 v0 = *(const uint4*)(x + (size_t)s0 * D + lane * 8);
        acc[0] += bf_lo(v0.x); acc[1] += bf_hi(v0.x);
        acc[2] += bf_lo(v0.y); acc[3] += bf_hi(v0.y);
        acc[4] += bf_lo(v0.z); acc[5] += bf_hi(v0.z);
        acc[6] += bf_lo(v0.w); acc[7] += bf_hi(v0.w);
    }
    uint4 o;
    o.x = ((unsigned)f2bf(acc[1]) << 16) | f2bf(acc[0]);
    o.y = ((unsigned)f2bf(acc[3]) << 16) | f2bf(acc[2]);
    o.z = ((unsigned)f2bf(acc[5]) << 16) | f2bf(acc[4]);
    o.w = ((unsigned)f2bf(acc[7]) << 16) | f2bf(acc[6]);
    *(uint4*)(out + (size_t)g * D + lane * 8) = o;
}

// ===========================================================================
// Fused 2-layer MLP, bf16 MFMA (32x32x16), 64 rows/block, 4 waves.
// A-tile staged in LDS (round-10 win); A unions with hid; LDS <=40KB.
// ===========================================================================
template<int LA, int LB, int LC, bool LSM>
__global__ __launch_bounds__(256)
void fused_mlp_mfma(const unsigned short* __restrict__ segA,
                    const unsigned short* __restrict__ segB,
                    const unsigned short* __restrict__ segC,
                    const unsigned short* __restrict__ WaT, const float* __restrict__ ba,
                    const unsigned short* __restrict__ WbT, const float* __restrict__ bb,
                    void* __restrict__ outv, int n) {
    constexpr int K1   = LA + LB + LC;      // 96 or 304
    constexpr int NS1  = K1 / 16;
    constexpr int NCH  = K1 / 8;            // 16B chunks per row
    constexpr int KPAD = K1 + 8;            // 104 or 312 (16B-aligned rows)
    constexpr int K2P  = 264;               // hid row stride (bf16)
    constexpr int SW   = (64 * KPAD > 64 * K2P) ? 64 * KPAD : 64 * K2P;
    __shared__ __attribute__((aligned(16))) unsigned short smem[SW];
    unsigned short* Ab  = smem;             // stage-1 A tile   [64][KPAD]
    unsigned short* hid = smem;             // stage-1 out      [64][K2P] (union)

    const int tid  = threadIdx.x;
    const int wave = tid >> 6;
    const int lane = tid & 63;
    const int l31  = lane & 31;
    const int lh   = lane >> 5;
    const int row0 = blockIdx.x * 64;

    // ---- stage A tile: coalesced uint4, ~10 independent loads/thread ----
    for (int c = tid; c < 64 * NCH; c += 256) {
        const int m  = c / NCH;
        const int kc = c - m * NCH;
        const int row = row0 + m;
        const int ra  = (row < n) ? row : (n - 1);
        const unsigned short* sp;
        int koff;
        if (kc * 8 < LA)           { sp = segA + (size_t)ra * LA; koff = kc * 8; }
        else if (kc * 8 < LA + LB) { sp = segB + (size_t)ra * LB; koff = kc * 8 - LA; }
        else                       { sp = segC + (size_t)ra * LC; koff = kc * 8 - LA - LB; }
        *(uint4*)(Ab + m * KPAD + kc * 8) = *(const uint4*)(sp + koff);
    }
    __syncthreads();

    // ---------------- stage 1 ----------------
    f32x16 acc00 = {}, acc01 = {}, acc10 = {}, acc11 = {};
    const unsigned short* wa0 = WaT + (size_t)(wave * 64 + l31) * K1 + lh * 8;
    const unsigned short* wa1 = wa0 + (size_t)32 * K1;
    const int a0off = l31 * KPAD + lh * 8;
    const int a1off = (l31 + 32) * KPAD + lh * 8;

    #pragma unroll
    for (int s = 0; s < NS1; ++s) {
        const int k0 = s * 16;
        s16x8 a0 = *(const s16x8*)(Ab + a0off + k0);
        s16x8 a1 = *(const s16x8*)(Ab + a1off + k0);
        s16x8 b0 = *(const s16x8*)(wa0 + k0);
        s16x8 b1 = *(const s16x8*)(wa1 + k0);
        acc00 = __builtin_amdgcn_mfma_f32_32x32x16_bf16(a0, b0, acc00, 0, 0, 0);
        acc01 = __builtin_amdgcn_mfma_f32_32x32x16_bf16(a0, b1, acc01, 0, 0, 0);
        acc10 = __builtin_amdgcn_mfma_f32_32x32x16_bf16(a1, b0, acc10, 0, 0, 0);
        acc11 = __builtin_amdgcn_mfma_f32_32x32x16_bf16(a1, b1, acc11, 0, 0, 0);
    }
    __syncthreads();                        // all A reads done before hid overwrites

    // epilogue: + bias, relu -> hid[m][k] bf16 (C/D layout, m74/m101)
    {
        const int c0 = wave * 64 + l31;
        const int c1 = c0 + 32;
        const float bias0 = ba[c0];
        const float bias1 = ba[c1];
        #pragma unroll
        for (int t = 0; t < 16; ++t) {
            int rloc = (t & 3) + 8 * (t >> 2) + 4 * lh;
            hid[rloc * K2P + c0]        = f2bf(fmaxf(acc00[t] + bias0, 0.f));
            hid[rloc * K2P + c1]        = f2bf(fmaxf(acc01[t] + bias1, 0.f));
            hid[(rloc + 32) * K2P + c0] = f2bf(fmaxf(acc10[t] + bias0, 0.f));
            hid[(rloc + 32) * K2P + c1] = f2bf(fmaxf(acc11[t] + bias1, 0.f));
        }
    }
    __syncthreads();

    // ---------------- stage 2 ----------------
    if (!LSM) {
        f32x16 d0 = {}, d1 = {};
        const unsigned short* wb = WbT + (size_t)(wave * 32 + l31) * 256 + lh * 8;
        const int h0 = l31 * K2P + lh * 8;
        #pragma unroll
        for (int s = 0; s < 16; ++s) {
            s16x8 a0 = *(const s16x8*)&hid[h0 + s * 16];
            s16x8 a1 = *(const s16x8*)&hid[h0 + 32 * K2P + s * 16];
            s16x8 b  = *(const s16x8*)(wb + s * 16);
            d0 = __builtin_amdgcn_mfma_f32_32x32x16_bf16(a0, b, d0, 0, 0, 0);
            d1 = __builtin_amdgcn_mfma_f32_32x32x16_bf16(a1, b, d1, 0, 0, 0);
        }
        const int col = wave * 32 + l31;
        const float bias = bb[col];
        unsigned short* out = (unsigned short*)outv;
        #pragma unroll
        for (int t = 0; t < 16; ++t) {
            int rloc = (t & 3) + 8 * (t >> 2) + 4 * lh;
            int rr0 = row0 + rloc, rr1 = rr0 + 32;
            if (rr0 < n) out[(size_t)rr0 * 128 + col] = f2bf(fmaxf(d0[t] + bias, 0.f));
            if (rr1 < n) out[(size_t)rr1 * 128 + col] = f2bf(fmaxf(d1[t] + bias, 0.f));
        }
    } else {
        const int rt = wave & 1, ct = wave >> 1;
        f32x16 d = {};
        const unsigned short* wb = WbT + (size_t)(ct * 32 + l31) * 256 + lh * 8;
        const int h0 = (rt * 32 + l31) * K2P + lh * 8;
        #pragma unroll
        for (int s = 0; s < 16; ++s) {
            s16x8 a = *(const s16x8*)&hid[h0 + s * 16];
            s16x8 b = *(const s16x8*)(wb + s * 16);
            d = __builtin_amdgcn_mfma_f32_32x32x16_bf16(a, b, d, 0, 0, 0);
        }
        __syncthreads();                    // done reading hid; reuse as logits
        float* lg = (float*)smem;           // [64][68] f32 = 17.4KB
        const int col = ct * 32 + l31;
        const float bias = (col < 40) ? bb[col] : 0.f;
        #pragma unroll
        for (int t = 0; t < 16; ++t) {
            int rloc = rt * 32 + (t & 3) + 8 * (t >> 2) + 4 * lh;
            lg[rloc * 68 + col] = d[t] + bias;
        }
        __syncthreads();
        const int r = tid >> 2, j = tid & 3;
        float mx = -1e30f;
        #pragma unroll
        for (int c = 0; c < 10; ++c) mx = fmaxf(mx, lg[r * 68 + j * 10 + c]);
        mx = fmaxf(mx, __shfl_xor(mx, 1));
        mx = fmaxf(mx, __shfl_xor(mx, 2));
        float sm = 0.f;
        #pragma unroll
        for (int c = 0; c < 10; ++c) sm += __expf(lg[r * 68 + j * 10 + c] - mx);
        sm += __shfl_xor(sm, 1);
        sm += __shfl_xor(sm, 2);
        const float lse = mx + __logf(sm);
        const int row = row0 + r;
        float* out = (float*)outv;
        if (row < n) {
            #pragma unroll
            for (int c = 0; c < 10; ++c)
                out[(size_t)row * 40 + j * 10 + c] = lg[r * 68 + j * 10 + c] - lse;
        }
    }
}

// ===========================================================================
extern "C" void kernel_launch(void* const* d_in, const int* in_sizes, int n_in,
                              void* d_out, int out_size, void* d_ws, size_t ws_size,
                              hipStream_t stream) {
    const float* x   = (const float*)d_in[0];
    const int*   ei  = (const int*)d_in[1];
    const float* W1a = (const float*)d_in[2];
    const float* b1a = (const float*)d_in[3];
    const float* W1b = (const float*)d_in[4];
    const float* b1b = (const float*)d_in[5];
    const float* W2a = (const float*)d_in[6];
    const float* b2a = (const float*)d_in[7];
    const float* W2b = (const float*)d_in[8];
    const float* b2b = (const float*)d_in[9];
    const float* W3a = (const float*)d_in[10];
    const float* b3a = (const float*)d_in[11];
    const float* W3b = (const float*)d_in[12];
    const float* b3b = (const float*)d_in[13];
    float* out = (float*)d_out;

    const int E = in_sizes[1] / 2;
    const int N = in_sizes[0] / 48;
    const int* src = ei;
    const int* dst = ei + E;

    // producers: C <= BMAX guaranteed
    int nprod = (E + BMAX - 1) / BMAX;
    if (nprod < 512) nprod = 512;
    const int C = (E + nprod - 1) / nprod;

    // ---- workspace carve-up (256B aligned) ----
    char* p = (char*)d_ws;
    auto alloc = [&](size_t bytes) { void* q = p; p += (bytes + 255) & ~(size_t)255; return q; };
    unsigned short* xbf  = (unsigned short*)alloc((size_t)N * 48  * 2);
    unsigned short* c1   = (unsigned short*)alloc((size_t)N * 48  * 2);
    unsigned short* h1   = (unsigned short*)alloc((size_t)N * 128 * 2);
    unsigned short* c2   = (unsigned short*)alloc((size_t)N * 128 * 2);  // also c3
    unsigned short* h2   = (unsigned short*)alloc((size_t)N * 128 * 2);
    unsigned short* W1aT = (unsigned short*)alloc((size_t)256 * 96  * 2);
    unsigned short* W1bT = (unsigned short*)alloc((size_t)128 * 256 * 2);
    unsigned short* W2aT = (unsigned short*)alloc((size_t)256 * 304 * 2);
    unsigned short* W2bT = (unsigned short*)alloc((size_t)128 * 256 * 2);
    unsigned short* W3aT = (unsigned short*)alloc((size_t)256 * 304 * 2);
    unsigned short* W3bT = (unsigned short*)alloc((size_t)64  * 256 * 2);
    int* deg     = (int*)alloc((size_t)N * 4);
    int* rowptr  = (int*)alloc((size_t)N * 4);
    int* cursor  = (int*)alloc((size_t)N * 4);
    int* bsum    = (int*)alloc(1024);
    int* csr_src = (int*)alloc((size_t)E * 4);
    int2* pairs  = (int2*)alloc((size_t)nprod * C * 8);
    int* offsg   = (int*)alloc((size_t)nprod * 9 * 4);

    const int nb_scan = (N + 1023) / 1024;
    const int nblk    = (N + 63) / 64;

    // ---- fused prep (x->bf16, 6 transposes, deg=0) ----
    {
        int total = N * 48 + N + 256*96 + 128*256 + 256*304 + 128*256 + 256*304 + 64*256;
        prep_fused<<<(total + 255) / 256, 256, 0, stream>>>(
            x, xbf, W1a, W1aT, W1b, W1bT, W2a, W2aT, W2b, W2bT,
            W3a, W3aT, W3b, W3bT, deg, N);
    }

    // ---- CSR build (bucketed two-phase) ----
    bucketize<<<nprod, 256, 0, stream>>>(src, dst, pairs, offsg, E, N, C);
    deg_from_buckets<<<2048, 256, 0, stream>>>(pairs, offsg, deg, nprod, C);
    scan_block_sums<<<nb_scan, 256, 0, stream>>>(deg, bsum, N);
    scan_bsums<<<1, 256, 0, stream>>>(bsum, nb_scan);
    scan_finalize<<<nb_scan, 256, 0, stream>>>(deg, bsum, rowptr, cursor, N);
    place_from_buckets<<<2048, 256, 0, stream>>>(pairs, offsg, cursor, csr_src, nprod, C, E);

    // ---- layer 1 ----
    lgconv_gather_bf16<48, 8><<<((size_t)N * 8 + 255) / 256, 256, 0, stream>>>(
        xbf, rowptr, deg, csr_src, c1, N);
    fused_mlp_mfma<48, 48, 0, false><<<nblk, 256, 0, stream>>>(
        c1, xbf, (const unsigned short*)nullptr, W1aT, b1a, W1bT, b1b, h1, N);

    // ---- layer 2 ----
    lgconv_gather_bf16<128, 16><<<((size_t)N * 16 + 255) / 256, 256, 0, stream>>>(
        h1, rowptr, deg, csr_src, c2, N);
    fused_mlp_mfma<128, 128, 48, false><<<nblk, 256, 0, stream>>>(
        c2, h1, xbf, W2aT, b2a, W2bT, b2b, h2, N);

    // ---- layer 3 ----
    lgconv_gather_bf16<128, 16><<<((size_t)N * 16 + 255) / 256, 256, 0, stream>>>(
        h2, rowptr, deg, csr_src, c2, N);   // c3 reuses c2 slot
    fused_mlp_mfma<128, 128, 48, true><<<nblk, 256, 0, stream>>>(
        c2, h2, xbf, W3aT, b3a, W3bT, b3b, out, N);
}

// Round 13
// 456.176 us; speedup vs baseline: 1.2601x; 1.2292x over previous
//
#include <hip/hip_runtime.h>
#include <math.h>

typedef __attribute__((ext_vector_type(8)))  short s16x8;   // 8 bf16 (4 VGPRs)
typedef __attribute__((ext_vector_type(16))) float f32x16;  // MFMA 32x32 acc

__device__ inline float bf_lo(unsigned u) { return __uint_as_float(u << 16); }
__device__ inline float bf_hi(unsigned u) { return __uint_as_float(u & 0xffff0000u); }
__device__ inline unsigned short f2bf(float f) {           // RNE f32 -> bf16
    unsigned u = __float_as_uint(f);
    u += 0x7fffu + ((u >> 16) & 1u);
    return (unsigned short)(u >> 16);
}

#define BMAX 3200   // max edges per producer chunk (LDS-resident)
#define RNG  512    // owner ranges (= producer count); per-range nodes <= 256

// ===========================================================================
// Fused prep: x f32->bf16, 6 weight transposes, deg zeroing. One dispatch.
// ===========================================================================
__global__ __launch_bounds__(256)
void prep_fused(const float* __restrict__ x,   unsigned short* __restrict__ xbf,
                const float* __restrict__ W1a, unsigned short* __restrict__ W1aT,
                const float* __restrict__ W1b, unsigned short* __restrict__ W1bT,
                const float* __restrict__ W2a, unsigned short* __restrict__ W2aT,
                const float* __restrict__ W2b, unsigned short* __restrict__ W2bT,
                const float* __restrict__ W3a, unsigned short* __restrict__ W3aT,
                const float* __restrict__ W3b, unsigned short* __restrict__ W3bT,
                int* __restrict__ deg, int N) {
    int i = blockIdx.x * 256 + threadIdx.x;
    int nx = N * 48;
    if (i < nx) { xbf[i] = f2bf(x[i]); return; }
    i -= nx;
    if (i < N) { deg[i] = 0; return; }
    i -= N;
    if (i < 256 * 96)  { int n = i / 96,  k = i - n * 96;  W1aT[i] = f2bf(W1a[(size_t)k * 256 + n]); return; }
    i -= 256 * 96;
    if (i < 128 * 256) { int n = i / 256, k = i - n * 256; W1bT[i] = f2bf(W1b[(size_t)k * 128 + n]); return; }
    i -= 128 * 256;
    if (i < 256 * 304) { int n = i / 304, k = i - n * 304; W2aT[i] = f2bf(W2a[(size_t)k * 256 + n]); return; }
    i -= 256 * 304;
    if (i < 128 * 256) { int n = i / 256, k = i - n * 256; W2bT[i] = f2bf(W2b[(size_t)k * 128 + n]); return; }
    i -= 128 * 256;
    if (i < 256 * 304) { int n = i / 304, k = i - n * 304; W3aT[i] = f2bf(W3a[(size_t)k * 256 + n]); return; }
    i -= 256 * 304;
    if (i < 64 * 256)  { int n = i / 256, k = i - n * 256;
                         float v = (n < 40) ? W3b[(size_t)k * 40 + n] : 0.f;
                         W3bT[i] = f2bf(v); return; }
}

// ===========================================================================
// CSR build, fully atomic-free-global design.
// Rounds 7-12 evidence: ALL multi-writer scatters (phased/xcd-filter/
// bucketed-8) converge to WRITE 66-91MB, dur 69-90us — the cross-XCD
// scattered write/atomic path is the invariant bound. Round 8 proved the
// LDS-cursor single-writer owner collapses WRITE to 15MB; its cost was
// full-edge-list re-reads. Fix: bucketize to 512 FINE ranges (producers
// compact once, block-private windows), owners then read only their ~3125
// edges and use LDS counters/cursors. Zero global atomics total.
// ===========================================================================
__global__ __launch_bounds__(256)
void bucketize(const int* __restrict__ src, const int* __restrict__ dst,
               int2* __restrict__ pairs, int* __restrict__ offsg,
               int E, int C, int per) {
    __shared__ int sdst[BMAX];
    __shared__ int ssrc[BMAX];
    __shared__ int cnt[RNG];
    __shared__ int cur[RNG + 1];
    __shared__ int sh[256];
    const int p    = blockIdx.x;
    const int base = p * C;
    const int len  = min(C, E - base);
    const int t    = threadIdx.x;

    cnt[t] = 0; cnt[t + 256] = 0;
    for (int i = t; i < len; i += 256) { sdst[i] = dst[base + i]; ssrc[i] = src[base + i]; }
    __syncthreads();
    for (int i = t; i < len; i += 256) {
        int r = sdst[i] / per;              // r <= (N-1)/per < RNG by construction
        atomicAdd(&cnt[r], 1);
    }
    __syncthreads();
    // exclusive scan of cnt[512] with 256 threads (pairs 2t,2t+1)
    const int cA = cnt[2 * t], cB = cnt[2 * t + 1];
    sh[t] = cA + cB;
    __syncthreads();
    for (int off = 1; off < 256; off <<= 1) {
        int add = (t >= off) ? sh[t - off] : 0;
        __syncthreads();
        sh[t] += add;
        __syncthreads();
    }
    const int excl = sh[t] - cA - cB;
    cur[2 * t] = excl;
    cur[2 * t + 1] = excl + cA;
    if (t == 255) cur[RNG] = sh[255];
    // offsets to global (from registers; no dependence on mutated cur)
    offsg[p * (RNG + 1) + 2 * t]     = excl;
    offsg[p * (RNG + 1) + 2 * t + 1] = excl + cA;
    if (t == 255) offsg[p * (RNG + 1) + RNG] = sh[255];
    __syncthreads();
    for (int i = t; i < len; i += 256) {
        int d = sdst[i];
        int r = d / per;
        int pos = atomicAdd(&cur[r], 1);
        pairs[base + pos] = make_int2(ssrc[i], d);
    }
}

// Owner consumers: block r owns nodes [r*per, r*per+per). Reads only its
// range's segments from each producer (LDS binary-search work distribution).
__global__ __launch_bounds__(256)
void deg_owned(const int2* __restrict__ pairs, const int* __restrict__ offsg,
               int* __restrict__ deg, int N, int C, int per) {
    __shared__ int po[RNG];
    __shared__ int W[RNG + 1];
    __shared__ int sh[256];
    __shared__ int dcnt[256];
    const int r  = blockIdx.x;
    const int lo = r * per;
    const int hi = min(lo + per, N);
    const int cnt = hi - lo;
    if (cnt <= 0) return;
    const int t = threadIdx.x;
    if (t < cnt) dcnt[t] = 0;
    const int pA = 2 * t, pB = 2 * t + 1;
    const int oA0 = offsg[pA * (RNG + 1) + r];
    const int oA1 = offsg[pA * (RNG + 1) + r + 1];
    const int oB0 = offsg[pB * (RNG + 1) + r];
    const int oB1 = offsg[pB * (RNG + 1) + r + 1];
    po[pA] = oA0; po[pB] = oB0;
    const int cA = oA1 - oA0, cB = oB1 - oB0;
    sh[t] = cA + cB;
    __syncthreads();
    for (int off = 1; off < 256; off <<= 1) {
        int add = (t >= off) ? sh[t - off] : 0;
        __syncthreads();
        sh[t] += add;
        __syncthreads();
    }
    const int excl = sh[t] - cA - cB;
    W[pA] = excl; W[pB] = excl + cA;
    if (t == 255) W[RNG] = sh[255];
    __syncthreads();
    const int tot = W[RNG];
    for (int i = t; i < tot; i += 256) {
        int a = 0, b = RNG;
        while (b - a > 1) { int m = (a + b) >> 1; if (W[m] <= i) a = m; else b = m; }
        const int2 pr = pairs[(size_t)a * C + po[a] + (i - W[a])];
        atomicAdd(&dcnt[pr.y - lo], 1);
    }
    __syncthreads();
    if (t < cnt) deg[lo + t] = dcnt[t];
}

__global__ __launch_bounds__(256)
void place_owned(const int2* __restrict__ pairs, const int* __restrict__ offsg,
                 const int* __restrict__ rowptr, int* __restrict__ csr_src,
                 int N, int C, int per, int E) {
    __shared__ int po[RNG];
    __shared__ int W[RNG + 1];
    __shared__ int sh[256];
    __shared__ int curs[256];
    const int r  = blockIdx.x;
    const int lo = r * per;
    const int hi = min(lo + per, N);
    const int cnt = hi - lo;
    if (cnt <= 0) return;
    const int t = threadIdx.x;
    if (t < cnt) curs[t] = rowptr[lo + t];   // fresh every launch: replay-safe
    const int pA = 2 * t, pB = 2 * t + 1;
    const int oA0 = offsg[pA * (RNG + 1) + r];
    const int oA1 = offsg[pA * (RNG + 1) + r + 1];
    const int oB0 = offsg[pB * (RNG + 1) + r];
    const int oB1 = offsg[pB * (RNG + 1) + r + 1];
    po[pA] = oA0; po[pB] = oB0;
    const int cA = oA1 - oA0, cB = oB1 - oB0;
    sh[t] = cA + cB;
    __syncthreads();
    for (int off = 1; off < 256; off <<= 1) {
        int add = (t >= off) ? sh[t - off] : 0;
        __syncthreads();
        sh[t] += add;
        __syncthreads();
    }
    const int excl = sh[t] - cA - cB;
    W[pA] = excl; W[pB] = excl + cA;
    if (t == 255) W[RNG] = sh[255];
    __syncthreads();
    const int tot = W[RNG];
    for (int i = t; i < tot; i += 256) {
        int a = 0, b = RNG;
        while (b - a > 1) { int m = (a + b) >> 1; if (W[m] <= i) a = m; else b = m; }
        const int2 pr = pairs[(size_t)a * C + po[a] + (i - W[a])];
        const int pos = atomicAdd(&curs[pr.y - lo], 1);   // LDS atomic
        if (pos < E) csr_src[pos] = pr.x;
    }
}

__global__ __launch_bounds__(256)
void scan_block_sums(const int* __restrict__ deg, int* __restrict__ bsum, int N) {
    __shared__ int sh[256];
    int base = blockIdx.x * 1024 + threadIdx.x * 4;
    int s = 0;
    #pragma unroll
    for (int k = 0; k < 4; ++k) { int i = base + k; if (i < N) s += deg[i]; }
    sh[threadIdx.x] = s;
    __syncthreads();
    for (int off = 128; off >= 1; off >>= 1) {
        if (threadIdx.x < off) sh[threadIdx.x] += sh[threadIdx.x + off];
        __syncthreads();
    }
    if (threadIdx.x == 0) bsum[blockIdx.x] = sh[0];
}

__global__ __launch_bounds__(256)
void scan_bsums(int* __restrict__ bsum, int nb) {
    __shared__ int sh[256];
    int t = threadIdx.x;
    int v = (t < nb) ? bsum[t] : 0;
    sh[t] = v;
    __syncthreads();
    for (int off = 1; off < 256; off <<= 1) {
        int add = (t >= off) ? sh[t - off] : 0;
        __syncthreads();
        sh[t] += add;
        __syncthreads();
    }
    if (t < nb) bsum[t] = sh[t] - v;
}

__global__ __launch_bounds__(256)
void scan_finalize(const int* __restrict__ deg, const int* __restrict__ bsum,
                   int* __restrict__ rowptr, int N) {
    __shared__ int sh[256];
    int t = threadIdx.x;
    int base = blockIdx.x * 1024 + t * 4;
    int loc[4];
    int s = 0;
    #pragma unroll
    for (int k = 0; k < 4; ++k) {
        int i = base + k;
        loc[k] = (i < N) ? deg[i] : 0;
        s += loc[k];
    }
    sh[t] = s;
    __syncthreads();
    for (int off = 1; off < 256; off <<= 1) {
        int add = (t >= off) ? sh[t - off] : 0;
        __syncthreads();
        sh[t] += add;
        __syncthreads();
    }
    int run = bsum[blockIdx.x] + sh[t] - s;
    #pragma unroll
    for (int k = 0; k < 4; ++k) {
        int i = base + k;
        if (i < N) rowptr[i] = run;
        run += loc[k];
    }
}

// ===========================================================================
// LGConv gather, bf16 in/out, f32 accumulate. 8 channels (16B) per lane.
// ===========================================================================
template<int D, int LPN>
__global__ __launch_bounds__(256)
void lgconv_gather_bf16(const unsigned short* __restrict__ x,
                        const int* __restrict__ rowptr,
                        const int* __restrict__ deg,
                        const int* __restrict__ csr_src,
                        unsigned short* __restrict__ out, int N) {
    const int g    = (blockIdx.x * 256 + threadIdx.x) / LPN;
    const int lane = threadIdx.x & (LPN - 1);
    if (g >= N) return;
    if (lane * 8 >= D) return;
    const int start = rowptr[g];
    const int dg    = deg[g];
    float acc[8] = {0.f,0.f,0.f,0.f,0.f,0.f,0.f,0.f};
    int j = 0;
    for (; j + 1 < dg; j += 2) {
        int s0 = csr_src[start + j];
        int s1 = csr_src[start + j + 1];
        uint4 v0 = *(const uint4*)(x + (size_t)s0 * D + lane * 8);
        uint4 v1 = *(const uint4*)(x + (size_t)s1 * D + lane * 8);
        acc[0] += bf_lo(v0.x); acc[1] += bf_hi(v0.x);
        acc[2] += bf_lo(v0.y); acc[3] += bf_hi(v0.y);
        acc[4] += bf_lo(v0.z); acc[5] += bf_hi(v0.z);
        acc[6] += bf_lo(v0.w); acc[7] += bf_hi(v0.w);
        acc[0] += bf_lo(v1.x); acc[1] += bf_hi(v1.x);
        acc[2] += bf_lo(v1.y); acc[3] += bf_hi(v1.y);
        acc[4] += bf_lo(v1.z); acc[5] += bf_hi(v1.z);
        acc[6] += bf_lo(v1.w); acc[7] += bf_hi(v1.w);
    }
    if (j < dg) {
        int s0 = csr_src[start + j];
        uint4 v0 = *(const uint4*)(x + (size_t)s0 * D + lane * 8);
        acc[0] += bf_lo(v0.x); acc[1] += bf_hi(v0.x);
        acc[2] += bf_lo(v0.y); acc[3] += bf_hi(v0.y);
        acc[4] += bf_lo(v0.z); acc[5] += bf_hi(v0.z);
        acc[6] += bf_lo(v0.w); acc[7] += bf_hi(v0.w);
    }
    uint4 o;
    o.x = ((unsigned)f2bf(acc[1]) << 16) | f2bf(acc[0]);
    o.y = ((unsigned)f2bf(acc[3]) << 16) | f2bf(acc[2]);
    o.z = ((unsigned)f2bf(acc[5]) << 16) | f2bf(acc[4]);
    o.w = ((unsigned)f2bf(acc[7]) << 16) | f2bf(acc[6]);
    *(uint4*)(out + (size_t)g * D + lane * 8) = o;
}

// ===========================================================================
// Fused 2-layer MLP, bf16 MFMA (32x32x16), 64 rows/block, 4 waves.
// A-tile staged in LDS (round-10 win); A unions with hid; LDS <=40KB.
// ===========================================================================
template<int LA, int LB, int LC, bool LSM>
__global__ __launch_bounds__(256)
void fused_mlp_mfma(const unsigned short* __restrict__ segA,
                    const unsigned short* __restrict__ segB,
                    const unsigned short* __restrict__ segC,
                    const unsigned short* __restrict__ WaT, const float* __restrict__ ba,
                    const unsigned short* __restrict__ WbT, const float* __restrict__ bb,
                    void* __restrict__ outv, int n) {
    constexpr int K1   = LA + LB + LC;      // 96 or 304
    constexpr int NS1  = K1 / 16;
    constexpr int NCH  = K1 / 8;            // 16B chunks per row
    constexpr int KPAD = K1 + 8;            // 104 or 312 (16B-aligned rows)
    constexpr int K2P  = 264;               // hid row stride (bf16)
    constexpr int SW   = (64 * KPAD > 64 * K2P) ? 64 * KPAD : 64 * K2P;
    __shared__ __attribute__((aligned(16))) unsigned short smem[SW];
    unsigned short* Ab  = smem;             // stage-1 A tile   [64][KPAD]
    unsigned short* hid = smem;             // stage-1 out      [64][K2P] (union)

    const int tid  = threadIdx.x;
    const int wave = tid >> 6;
    const int lane = tid & 63;
    const int l31  = lane & 31;
    const int lh   = lane >> 5;
    const int row0 = blockIdx.x * 64;

    // ---- stage A tile: coalesced uint4, ~10 independent loads/thread ----
    for (int c = tid; c < 64 * NCH; c += 256) {
        const int m  = c / NCH;
        const int kc = c - m * NCH;
        const int row = row0 + m;
        const int ra  = (row < n) ? row : (n - 1);
        const unsigned short* sp;
        int koff;
        if (kc * 8 < LA)           { sp = segA + (size_t)ra * LA; koff = kc * 8; }
        else if (kc * 8 < LA + LB) { sp = segB + (size_t)ra * LB; koff = kc * 8 - LA; }
        else                       { sp = segC + (size_t)ra * LC; koff = kc * 8 - LA - LB; }
        *(uint4*)(Ab + m * KPAD + kc * 8) = *(const uint4*)(sp + koff);
    }
    __syncthreads();

    // ---------------- stage 1 ----------------
    f32x16 acc00 = {}, acc01 = {}, acc10 = {}, acc11 = {};
    const unsigned short* wa0 = WaT + (size_t)(wave * 64 + l31) * K1 + lh * 8;
    const unsigned short* wa1 = wa0 + (size_t)32 * K1;
    const int a0off = l31 * KPAD + lh * 8;
    const int a1off = (l31 + 32) * KPAD + lh * 8;

    #pragma unroll
    for (int s = 0; s < NS1; ++s) {
        const int k0 = s * 16;
        s16x8 a0 = *(const s16x8*)(Ab + a0off + k0);
        s16x8 a1 = *(const s16x8*)(Ab + a1off + k0);
        s16x8 b0 = *(const s16x8*)(wa0 + k0);
        s16x8 b1 = *(const s16x8*)(wa1 + k0);
        acc00 = __builtin_amdgcn_mfma_f32_32x32x16_bf16(a0, b0, acc00, 0, 0, 0);
        acc01 = __builtin_amdgcn_mfma_f32_32x32x16_bf16(a0, b1, acc01, 0, 0, 0);
        acc10 = __builtin_amdgcn_mfma_f32_32x32x16_bf16(a1, b0, acc10, 0, 0, 0);
        acc11 = __builtin_amdgcn_mfma_f32_32x32x16_bf16(a1, b1, acc11, 0, 0, 0);
    }
    __syncthreads();                        // all A reads done before hid overwrites

    // epilogue: + bias, relu -> hid[m][k] bf16 (C/D layout, m74/m101)
    {
        const int c0 = wave * 64 + l31;
        const int c1 = c0 + 32;
        const float bias0 = ba[c0];
        const float bias1 = ba[c1];
        #pragma unroll
        for (int t = 0; t < 16; ++t) {
            int rloc = (t & 3) + 8 * (t >> 2) + 4 * lh;
            hid[rloc * K2P + c0]        = f2bf(fmaxf(acc00[t] + bias0, 0.f));
            hid[rloc * K2P + c1]        = f2bf(fmaxf(acc01[t] + bias1, 0.f));
            hid[(rloc + 32) * K2P + c0] = f2bf(fmaxf(acc10[t] + bias0, 0.f));
            hid[(rloc + 32) * K2P + c1] = f2bf(fmaxf(acc11[t] + bias1, 0.f));
        }
    }
    __syncthreads();

    // ---------------- stage 2 ----------------
    if (!LSM) {
        f32x16 d0 = {}, d1 = {};
        const unsigned short* wb = WbT + (size_t)(wave * 32 + l31) * 256 + lh * 8;
        const int h0 = l31 * K2P + lh * 8;
        #pragma unroll
        for (int s = 0; s < 16; ++s) {
            s16x8 a0 = *(const s16x8*)&hid[h0 + s * 16];
            s16x8 a1 = *(const s16x8*)&hid[h0 + 32 * K2P + s * 16];
            s16x8 b  = *(const s16x8*)(wb + s * 16);
            d0 = __builtin_amdgcn_mfma_f32_32x32x16_bf16(a0, b, d0, 0, 0, 0);
            d1 = __builtin_amdgcn_mfma_f32_32x32x16_bf16(a1, b, d1, 0, 0, 0);
        }
        const int col = wave * 32 + l31;
        const float bias = bb[col];
        unsigned short* out = (unsigned short*)outv;
        #pragma unroll
        for (int t = 0; t < 16; ++t) {
            int rloc = (t & 3) + 8 * (t >> 2) + 4 * lh;
            int rr0 = row0 + rloc, rr1 = rr0 + 32;
            if (rr0 < n) out[(size_t)rr0 * 128 + col] = f2bf(fmaxf(d0[t] + bias, 0.f));
            if (rr1 < n) out[(size_t)rr1 * 128 + col] = f2bf(fmaxf(d1[t] + bias, 0.f));
        }
    } else {
        const int rt = wave & 1, ct = wave >> 1;
        f32x16 d = {};
        const unsigned short* wb = WbT + (size_t)(ct * 32 + l31) * 256 + lh * 8;
        const int h0 = (rt * 32 + l31) * K2P + lh * 8;
        #pragma unroll
        for (int s = 0; s < 16; ++s) {
            s16x8 a = *(const s16x8*)&hid[h0 + s * 16];
            s16x8 b = *(const s16x8*)(wb + s * 16);
            d = __builtin_amdgcn_mfma_f32_32x32x16_bf16(a, b, d, 0, 0, 0);
        }
        __syncthreads();                    // done reading hid; reuse as logits
        float* lg = (float*)smem;           // [64][68] f32 = 17.4KB
        const int col = ct * 32 + l31;
        const float bias = (col < 40) ? bb[col] : 0.f;
        #pragma unroll
        for (int t = 0; t < 16; ++t) {
            int rloc = rt * 32 + (t & 3) + 8 * (t >> 2) + 4 * lh;
            lg[rloc * 68 + col] = d[t] + bias;
        }
        __syncthreads();
        const int r = tid >> 2, j = tid & 3;
        float mx = -1e30f;
        #pragma unroll
        for (int c = 0; c < 10; ++c) mx = fmaxf(mx, lg[r * 68 + j * 10 + c]);
        mx = fmaxf(mx, __shfl_xor(mx, 1));
        mx = fmaxf(mx, __shfl_xor(mx, 2));
        float sm = 0.f;
        #pragma unroll
        for (int c = 0; c < 10; ++c) sm += __expf(lg[r * 68 + j * 10 + c] - mx);
        sm += __shfl_xor(sm, 1);
        sm += __shfl_xor(sm, 2);
        const float lse = mx + __logf(sm);
        const int row = row0 + r;
        float* out = (float*)outv;
        if (row < n) {
            #pragma unroll
            for (int c = 0; c < 10; ++c)
                out[(size_t)row * 40 + j * 10 + c] = lg[r * 68 + j * 10 + c] - lse;
        }
    }
}

// ===========================================================================
extern "C" void kernel_launch(void* const* d_in, const int* in_sizes, int n_in,
                              void* d_out, int out_size, void* d_ws, size_t ws_size,
                              hipStream_t stream) {
    const float* x   = (const float*)d_in[0];
    const int*   ei  = (const int*)d_in[1];
    const float* W1a = (const float*)d_in[2];
    const float* b1a = (const float*)d_in[3];
    const float* W1b = (const float*)d_in[4];
    const float* b1b = (const float*)d_in[5];
    const float* W2a = (const float*)d_in[6];
    const float* b2a = (const float*)d_in[7];
    const float* W2b = (const float*)d_in[8];
    const float* b2b = (const float*)d_in[9];
    const float* W3a = (const float*)d_in[10];
    const float* b3a = (const float*)d_in[11];
    const float* W3b = (const float*)d_in[12];
    const float* b3b = (const float*)d_in[13];
    float* out = (float*)d_out;

    const int E = in_sizes[1] / 2;
    const int N = in_sizes[0] / 48;
    const int* src = ei;
    const int* dst = ei + E;

    const int nprod = RNG;                      // 512 producers == 512 owners
    const int C     = (E + nprod - 1) / nprod;  // 3125 for E=1.6M (<= BMAX)
    const int per   = (N + RNG - 1) / RNG;      // 196 nodes/owner (<= 256)

    // ---- workspace carve-up (256B aligned) ----
    char* p = (char*)d_ws;
    auto alloc = [&](size_t bytes) { void* q = p; p += (bytes + 255) & ~(size_t)255; return q; };
    unsigned short* xbf  = (unsigned short*)alloc((size_t)N * 48  * 2);
    unsigned short* c1   = (unsigned short*)alloc((size_t)N * 48  * 2);
    unsigned short* h1   = (unsigned short*)alloc((size_t)N * 128 * 2);
    unsigned short* c2   = (unsigned short*)alloc((size_t)N * 128 * 2);  // also c3
    unsigned short* h2   = (unsigned short*)alloc((size_t)N * 128 * 2);
    unsigned short* W1aT = (unsigned short*)alloc((size_t)256 * 96  * 2);
    unsigned short* W1bT = (unsigned short*)alloc((size_t)128 * 256 * 2);
    unsigned short* W2aT = (unsigned short*)alloc((size_t)256 * 304 * 2);
    unsigned short* W2bT = (unsigned short*)alloc((size_t)128 * 256 * 2);
    unsigned short* W3aT = (unsigned short*)alloc((size_t)256 * 304 * 2);
    unsigned short* W3bT = (unsigned short*)alloc((size_t)64  * 256 * 2);
    int* deg     = (int*)alloc((size_t)N * 4);
    int* rowptr  = (int*)alloc((size_t)N * 4);
    int* bsum    = (int*)alloc(1024);
    int* csr_src = (int*)alloc((size_t)E * 4);
    int2* pairs  = (int2*)alloc((size_t)nprod * C * 8);
    int* offsg   = (int*)alloc((size_t)nprod * (RNG + 1) * 4);

    const int nb_scan = (N + 1023) / 1024;
    const int nblk    = (N + 63) / 64;

    // ---- fused prep (x->bf16, 6 transposes, deg=0) ----
    {
        int total = N * 48 + N + 256*96 + 128*256 + 256*304 + 128*256 + 256*304 + 64*256;
        prep_fused<<<(total + 255) / 256, 256, 0, stream>>>(
            x, xbf, W1a, W1aT, W1b, W1bT, W2a, W2aT, W2b, W2bT,
            W3a, W3aT, W3b, W3bT, deg, N);
    }

    // ---- CSR build (bucketize -> owned deg -> scan -> owned place) ----
    bucketize<<<nprod, 256, 0, stream>>>(src, dst, pairs, offsg, E, C, per);
    deg_owned<<<RNG, 256, 0, stream>>>(pairs, offsg, deg, N, C, per);
    scan_block_sums<<<nb_scan, 256, 0, stream>>>(deg, bsum, N);
    scan_bsums<<<1, 256, 0, stream>>>(bsum, nb_scan);
    scan_finalize<<<nb_scan, 256, 0, stream>>>(deg, bsum, rowptr, N);
    place_owned<<<RNG, 256, 0, stream>>>(pairs, offsg, rowptr, csr_src, N, C, per, E);

    // ---- layer 1 ----
    lgconv_gather_bf16<48, 8><<<((size_t)N * 8 + 255) / 256, 256, 0, stream>>>(
        xbf, rowptr, deg, csr_src, c1, N);
    fused_mlp_mfma<48, 48, 0, false><<<nblk, 256, 0, stream>>>(
        c1, xbf, (const unsigned short*)nullptr, W1aT, b1a, W1bT, b1b, h1, N);

    // ---- layer 2 ----
    lgconv_gather_bf16<128, 16><<<((size_t)N * 16 + 255) / 256, 256, 0, stream>>>(
        h1, rowptr, deg, csr_src, c2, N);
    fused_mlp_mfma<128, 128, 48, false><<<nblk, 256, 0, stream>>>(
        c2, h1, xbf, W2aT, b2a, W2bT, b2b, h2, N);

    // ---- layer 3 ----
    lgconv_gather_bf16<128, 16><<<((size_t)N * 16 + 255) / 256, 256, 0, stream>>>(
        h2, rowptr, deg, csr_src, c2, N);   // c3 reuses c2 slot
    fused_mlp_mfma<128, 128, 48, true><<<nblk, 256, 0, stream>>>(
        c2, h2, xbf, W3aT, b3a, W3bT, b3b, out, N);
}